// Round 4
// baseline (400.728 us; speedup 1.0000x reference)
//
#include <hip/hip_runtime.h>

typedef unsigned short u16;
typedef __attribute__((ext_vector_type(4))) short short4v;
typedef __attribute__((ext_vector_type(8))) short short8;
typedef __attribute__((ext_vector_type(4))) float f32x4;

#define MB_ (1024 * 1024)

__device__ __forceinline__ u16 f2bf(float f) {
  union { float f; unsigned int u; } v; v.f = f;
  unsigned int r = (v.u + 0x7FFFu + ((v.u >> 16) & 1u)) >> 16;  // RNE
  return (u16)r;
}

// pack two fp32 -> two bf16 (round-half-up) in one dword: low16 = a, high16 = b
__device__ __forceinline__ unsigned int pkbf(float a, float b) {
  union { float f; unsigned int u; } x, y; x.f = a; y.f = b;
  return __builtin_amdgcn_perm(y.u + 0x8000u, x.u + 0x8000u, 0x07060302u);
}

__device__ __forceinline__ void async16(const void* g, void* l) {
  __builtin_amdgcn_global_load_lds((__attribute__((address_space(1))) void*)g,
                                   (__attribute__((address_space(3))) void*)l, 16, 0, 0);
}

__device__ __forceinline__ f32x4 mfma32(short8 a, short8 b, f32x4 c) {
  return __builtin_amdgcn_mfma_f32_16x16x32_bf16(a, b, c, 0, 0, 0);
}

// ---------------- kernel 1: fp32 -> bf16 for the three activations ----------------
__global__ void cvt_x(const float* __restrict__ a, const float* __restrict__ b,
                      const float* __restrict__ c, u16* __restrict__ oa,
                      u16* __restrict__ ob, u16* __restrict__ oc) {
  const float* s = blockIdx.y == 0 ? a : (blockIdx.y == 1 ? b : c);
  u16* d = blockIdx.y == 0 ? oa : (blockIdx.y == 1 ? ob : oc);
  size_t i = ((size_t)blockIdx.x * 256 + threadIdx.x) * 4;
  float4 f = *(const float4*)&s[i];
  ushort4 o;
  o.x = f2bf(f.x); o.y = f2bf(f.y); o.z = f2bf(f.z); o.w = f2bf(f.w);
  *(ushort4*)&d[i] = o;
}

// ---------------- kernel 2: weight transpose + convert: W[k][n] -> Wt[n][k] bf16 ----
__global__ void wtrans(const float* __restrict__ w0, const float* __restrict__ w1,
                       const float* __restrict__ w2, const float* __restrict__ w3,
                       u16* __restrict__ o0, u16* __restrict__ o1,
                       u16* __restrict__ o2, u16* __restrict__ o3) {
  const int z = blockIdx.z;
  const float* in = z == 0 ? w0 : (z == 1 ? w1 : (z == 2 ? w2 : w3));
  u16* out = z == 0 ? o0 : (z == 1 ? o1 : (z == 2 ? o2 : o3));
  __shared__ float tile[32][33];
  const int bx = blockIdx.x * 32, by = blockIdx.y * 32;
  for (int i = threadIdx.y; i < 32; i += 8)
    tile[i][threadIdx.x] = in[(size_t)(by + i) * 1024 + bx + threadIdx.x];
  __syncthreads();
  for (int i = threadIdx.y; i < 32; i += 8)
    out[(size_t)(bx + i) * 1024 + by + threadIdx.x] = f2bf(tile[threadIdx.x][i]);
}

// ---------------- GEMM: C[8192,1024] = A[8192,1024] @ Bt[1024,1024]^T + bias ------
// m97 structure: 128x128 tile, BK=32, global_load_lds width 16, 4 waves, 4x4 MFMA/wave
// mode 0: fp32 [m][n];  mode 1: bf16 split [B,H,S,DK];  mode 2: bf16 V^T [B,H,DK,S]
__device__ __forceinline__ void gemm_body(const u16* __restrict__ A, const u16* __restrict__ Bt,
                                          const float* __restrict__ bias, float alpha,
                                          int mode, void* __restrict__ outp) {
  __shared__ __align__(16) u16 As[128 * 32];
  __shared__ __align__(16) u16 Bs[128 * 32];
  const int t = threadIdx.x, wave = t >> 6, lane = t & 63;
  const int m0 = blockIdx.y * 128, n0 = blockIdx.x * 128;
  const int wm = (wave >> 1) * 64, wn = (wave & 1) * 64;
  const int lrow = lane >> 2, lcol = (lane & 3) * 8;
  f32x4 acc[4][4] = {};
  for (int k0 = 0; k0 < 1024; k0 += 32) {
    __syncthreads();
#pragma unroll
    for (int c = 0; c < 2; ++c) {
      const int chunk = wave * 2 + c;
      const int row = chunk * 16 + lrow;
      async16(&A[(size_t)(m0 + row) * 1024 + k0 + lcol], &As[chunk * 512]);
      async16(&Bt[(size_t)(n0 + row) * 1024 + k0 + lcol], &Bs[chunk * 512]);
    }
    __syncthreads();
    short8 af[4], bf[4];
#pragma unroll
    for (int mb = 0; mb < 4; ++mb)
      af[mb] = *(const short8*)&As[(wm + mb * 16 + (lane & 15)) * 32 + (lane >> 4) * 8];
#pragma unroll
    for (int nb = 0; nb < 4; ++nb)
      bf[nb] = *(const short8*)&Bs[(wn + nb * 16 + (lane & 15)) * 32 + (lane >> 4) * 8];
#pragma unroll
    for (int mb = 0; mb < 4; ++mb)
#pragma unroll
      for (int nb = 0; nb < 4; ++nb)
        acc[mb][nb] = mfma32(af[mb], bf[nb], acc[mb][nb]);
  }
#pragma unroll
  for (int mb = 0; mb < 4; ++mb)
#pragma unroll
    for (int nb = 0; nb < 4; ++nb) {
      const int n = n0 + wn + nb * 16 + (lane & 15);
      const float bn = bias[n];
      if (mode == 2) {
        // V^T [B*H, DK, S]: r -> s contiguous, pack 4 into one 8B store
        const int h = n >> 6, d = n & 63;
        const int mbase = m0 + wm + mb * 16 + (lane >> 4) * 4;
        const int b = mbase >> 11, s = mbase & 2047;
        union { unsigned int u[2]; ushort4 s4; } pk;
        pk.u[0] = pkbf(acc[mb][nb][0] + bn, acc[mb][nb][1] + bn);
        pk.u[1] = pkbf(acc[mb][nb][2] + bn, acc[mb][nb][3] + bn);
        *(ushort4*)&((u16*)outp)[(size_t)((b * 16 + h) * 64 + d) * 2048 + s] = pk.s4;
      } else if (mode == 1) {
#pragma unroll
        for (int r = 0; r < 4; ++r) {
          const int m = m0 + wm + mb * 16 + (lane >> 4) * 4 + r;
          const int b = m >> 11, s = m & 2047, h = n >> 6, d = n & 63;
          ((u16*)outp)[(size_t)((b * 16 + h) * 2048 + s) * 64 + d] =
              (u16)(pkbf(acc[mb][nb][r] * alpha + bn * alpha, 0.f) & 0xFFFFu);
        }
      } else {
#pragma unroll
        for (int r = 0; r < 4; ++r) {
          const int m = m0 + wm + mb * 16 + (lane >> 4) * 4 + r;
          ((float*)outp)[(size_t)m * 1024 + n] = acc[mb][nb][r] + bn;
        }
      }
    }
}

__global__ __launch_bounds__(256, 2) void gemm_proj(
    const u16* xq, const u16* xk, const u16* xv,
    const u16* wq, const u16* wk, const u16* wv,
    const float* bq, const float* bk, const float* bv,
    u16* oq, u16* ok, u16* ov, float aq) {
  const int z = blockIdx.z;
  const u16* A = z == 0 ? xq : (z == 1 ? xk : xv);
  const u16* B = z == 0 ? wq : (z == 1 ? wk : wv);
  const float* bi = z == 0 ? bq : (z == 1 ? bk : bv);
  void* o = z == 0 ? (void*)oq : (z == 1 ? (void*)ok : (void*)ov);
  gemm_body(A, B, bi, z == 0 ? aq : 1.0f, z == 2 ? 2 : 1, o);
}

__global__ __launch_bounds__(256, 2) void gemm_out(const u16* A, const u16* Bt,
                                                   const float* bias, float* o) {
  gemm_body(A, Bt, bias, 1.0f, 0, o);
}

// ---------------- kernel 4: flash attention, S^T formulation, 64-q blocks --------
// grid (S/64, B*H); block 256 = 4 waves; wave owns 16 q rows (one q-group).
// No online max (logits bounded; softmax shift-invariant). l summed once at end.
// V arrives pre-transposed [B,H,DK,S]; K and V^T stage via async16 DMA.
// LDS XOR-chunk swizzle: 16B chunk c of row r at position c^(r&7).
__global__ __launch_bounds__(256, 8) void flash_attn(const u16* __restrict__ Q,
                                                     const u16* __restrict__ K,
                                                     const u16* __restrict__ Vt,
                                                     u16* __restrict__ O) {
  __shared__ __align__(16) u16 lds[2 * 64 * 64];  // Ks [s][d] | Vs [d][s], swizzled
  u16* Ks = lds;
  u16* Vs = lds + 4096;
  const int t = threadIdx.x, wave = t >> 6, lane = t & 63;
  const int quad = lane >> 4, q15 = lane & 15, sw = q15 & 7;
  const int bh = blockIdx.y, q0 = blockIdx.x * 64;
  const u16* Qb = Q + (size_t)bh * 2048 * 64;
  const u16* Kb = K + (size_t)bh * 2048 * 64;
  const u16* Vb = Vt + (size_t)bh * 64 * 2048;
  // Q B-fragments, held all loop: B[n=q][k=d]
  const int qr = q0 + wave * 16 + q15;
  const short8 qf0 = *(const short8*)&Qb[(size_t)qr * 64 + quad * 8];
  const short8 qf1 = *(const short8*)&Qb[(size_t)qr * 64 + 32 + quad * 8];
  f32x4 oacc[4] = {};  // O^T[d = mb*16 + quad*4 + r][q = lane&15]
  float l = 0.f;
  for (int kc = 0; kc < 2048; kc += 64) {
    __syncthreads();
#pragma unroll
    for (int c = 0; c < 2; ++c) {
      const int i = wave * 2 + c;
      const int row = i * 8 + (lane >> 3);          // s-row for K, d-row for V^T
      const int ch = (lane & 7) ^ (row & 7);        // swizzle via SOURCE permutation
      async16(&Kb[(size_t)(kc + row) * 64 + ch * 8], &Ks[i * 512]);
      async16(&Vb[(size_t)row * 2048 + kc + ch * 8], &Vs[i * 512]);
    }
    __syncthreads();
    short4v pk[4];  // P^T C-frag == 16x16x16 B-frag — no LDS round-trip
#pragma unroll
    for (int ma = 0; ma < 4; ++ma) {
      const int rowo = (ma * 16 + q15) * 64;
      const short8 k0 = *(const short8*)&Ks[rowo + ((quad ^ sw) * 8)];
      const short8 k1 = *(const short8*)&Ks[rowo + (((4 + quad) ^ sw) * 8)];
      f32x4 s0 = {};
      s0 = mfma32(k0, qf0, s0);
      s0 = mfma32(k1, qf1, s0);
      float p0 = __builtin_exp2f(s0[0]);
      float p1 = __builtin_exp2f(s0[1]);
      float p2 = __builtin_exp2f(s0[2]);
      float p3 = __builtin_exp2f(s0[3]);
      l += (p0 + p1) + (p2 + p3);
      union { unsigned int u[2]; short4v s4; } pq;
      pq.u[0] = pkbf(p0, p1);
      pq.u[1] = pkbf(p2, p3);
      pk[ma] = pq.s4;
    }
    // O^T += V^T · P^T
#if __has_builtin(__builtin_amdgcn_mfma_f32_16x16x16bf16_1k)
#pragma unroll
    for (int mb = 0; mb < 4; ++mb) {
      const int vrow = (mb * 16 + q15) * 64;
#pragma unroll
      for (int kb = 0; kb < 4; ++kb) {
        const int pos = (((kb * 2 + (quad >> 1)) ^ sw) * 8) + (quad & 1) * 4;
        const short4v vf = *(const short4v*)&Vs[vrow + pos];
        oacc[mb] = __builtin_amdgcn_mfma_f32_16x16x16bf16_1k(vf, pk[kb], oacc[mb], 0, 0, 0);
      }
    }
#else
    // fallback: assemble x32 B-frags from pk via shuffles
    {
      const int* pi = (const int*)&pk[0];
#pragma unroll
      for (int kb2 = 0; kb2 < 2; ++kb2) {
        const int lo = quad < 2 ? pi[kb2 * 4 + 0] : pi[kb2 * 4 + 2];
        const int hi = quad < 2 ? pi[kb2 * 4 + 1] : pi[kb2 * 4 + 3];
        const int src = (2 * (quad & 1)) * 16 + q15;
        union { int i[4]; short8 s; } u;
        u.i[0] = __shfl(lo, src);      u.i[1] = __shfl(hi, src);
        u.i[2] = __shfl(lo, src + 16); u.i[3] = __shfl(hi, src + 16);
#pragma unroll
        for (int mb = 0; mb < 4; ++mb) {
          const short8 vf8 = *(const short8*)&Vs[(mb * 16 + q15) * 64 + (((kb2 * 4 + quad) ^ sw) * 8)];
          oacc[mb] = mfma32(vf8, u.s, oacc[mb]);
        }
      }
    }
#endif
  }
  l += __shfl_xor(l, 16);
  l += __shfl_xor(l, 32);
  const float inv = 1.f / l;
  // epilogue: un-transpose O^T via per-wave LDS tile (16x64), write [B,S,H*DK] bf16
  __syncthreads();               // other waves done reading Ks/Vs of last chunk
  u16* Es = lds + wave * 1024;   // 2 KB per wave
#pragma unroll
  for (int mb = 0; mb < 4; ++mb) {
    const int posc = ((mb * 2 + (quad >> 1)) ^ sw) * 8 + (quad & 1) * 4;
    union { unsigned int u[2]; ushort4 s4; } pq;
    pq.u[0] = pkbf(oacc[mb][0] * inv, oacc[mb][1] * inv);
    pq.u[1] = pkbf(oacc[mb][2] * inv, oacc[mb][3] * inv);
    *(ushort4*)&Es[q15 * 64 + posc] = pq.s4;
  }
  // wave-local write->read: compiler inserts lgkmcnt wait; no cross-wave dependency
  const int b = bh >> 4, h = bh & 15;
#pragma unroll
  for (int pass = 0; pass < 2; ++pass) {
    const int rw = pass * 8 + (lane >> 3);
    const int j = lane & 7;
    const short8 val = *(const short8*)&Es[rw * 64 + ((j ^ (rw & 7)) * 8)];
    *(short8*)&O[((size_t)(b * 2048 + q0 + wave * 16 + rw)) * 1024 + h * 64 + j * 8] = val;
  }
}

// ---------------- host launcher ----------------
extern "C" void kernel_launch(void* const* d_in, const int* in_sizes, int n_in,
                              void* d_out, int out_size, void* d_ws, size_t ws_size,
                              hipStream_t stream) {
  const float* q_in = (const float*)d_in[0];
  const float* v_in = (const float*)d_in[1];
  const float* k_in = (const float*)d_in[2];
  const float* Wq = (const float*)d_in[3];
  const float* bq = (const float*)d_in[4];
  const float* Wk = (const float*)d_in[5];
  const float* bk = (const float*)d_in[6];
  const float* Wv = (const float*)d_in[7];
  const float* bv = (const float*)d_in[8];
  const float* Wo = (const float*)d_in[9];
  const float* bo = (const float*)d_in[10];
  float* out = (float*)d_out;
  char* ws = (char*)d_ws;

  u16* xq = (u16*)(ws);                 // 16 MB  (bf16 activations)
  u16* xk = (u16*)(ws + 16 * (size_t)MB_);
  u16* xv = (u16*)(ws + 32 * (size_t)MB_);
  u16* wqT = (u16*)(ws + 48 * (size_t)MB_);  // 2 MB each (bf16 W^T)
  u16* wkT = (u16*)(ws + 50 * (size_t)MB_);
  u16* wvT = (u16*)(ws + 52 * (size_t)MB_);
  u16* woT = (u16*)(ws + 54 * (size_t)MB_);
  u16* qb = (u16*)(ws + 56 * (size_t)MB_);   // [B,H,S,DK] bf16
  u16* kb = (u16*)(ws + 72 * (size_t)MB_);   // [B,H,S,DK] bf16
  u16* vb = (u16*)(ws + 88 * (size_t)MB_);   // [B,H,DK,S] bf16 (pre-transposed)
  u16* ao = xq;  // attention output reuses xq (dead after projections)

  // fold softmax scale and log2(e) into Q so the inner loop uses raw exp2
  const float aq = 0.125f * 1.44269504088896340736f;

  cvt_x<<<dim3(8192, 3), 256, 0, stream>>>(q_in, k_in, v_in, xq, xk, xv);
  wtrans<<<dim3(32, 32, 4), dim3(32, 8), 0, stream>>>(Wq, Wk, Wv, Wo, wqT, wkT, wvT, woT);
  gemm_proj<<<dim3(8, 64, 3), 256, 0, stream>>>(xq, xk, xv, wqT, wkT, wvT, bq, bk, bv, qb, kb, vb, aq);
  flash_attn<<<dim3(32, 64), 256, 0, stream>>>(qb, kb, vb, ao);
  gemm_out<<<dim3(8, 64), 256, 0, stream>>>(ao, woT, bo, out);
}

// Round 5
// 388.726 us; speedup vs baseline: 1.0309x; 1.0309x over previous
//
#include <hip/hip_runtime.h>

typedef unsigned short u16;
typedef __attribute__((ext_vector_type(4))) short short4v;
typedef __attribute__((ext_vector_type(8))) short short8;
typedef __attribute__((ext_vector_type(4))) float f32x4;

#define MB_ (1024 * 1024)

__device__ __forceinline__ u16 f2bf(float f) {
  union { float f; unsigned int u; } v; v.f = f;
  unsigned int r = (v.u + 0x7FFFu + ((v.u >> 16) & 1u)) >> 16;  // RNE
  return (u16)r;
}

// pack two fp32 -> two bf16 (round-half-up) in one dword: low16 = a, high16 = b
__device__ __forceinline__ unsigned int pkbf(float a, float b) {
  union { float f; unsigned int u; } x, y; x.f = a; y.f = b;
  return __builtin_amdgcn_perm(y.u + 0x8000u, x.u + 0x8000u, 0x07060302u);
}

__device__ __forceinline__ void async16(const void* g, void* l) {
  __builtin_amdgcn_global_load_lds((__attribute__((address_space(1))) void*)g,
                                   (__attribute__((address_space(3))) void*)l, 16, 0, 0);
}

__device__ __forceinline__ f32x4 mfma32(short8 a, short8 b, f32x4 c) {
  return __builtin_amdgcn_mfma_f32_16x16x32_bf16(a, b, c, 0, 0, 0);
}

// ---------------- kernel 1: fp32 -> bf16 for the three activations ----------------
__global__ void cvt_x(const float* __restrict__ a, const float* __restrict__ b,
                      const float* __restrict__ c, u16* __restrict__ oa,
                      u16* __restrict__ ob, u16* __restrict__ oc) {
  const float* s = blockIdx.y == 0 ? a : (blockIdx.y == 1 ? b : c);
  u16* d = blockIdx.y == 0 ? oa : (blockIdx.y == 1 ? ob : oc);
  size_t i = ((size_t)blockIdx.x * 256 + threadIdx.x) * 4;
  float4 f = *(const float4*)&s[i];
  ushort4 o;
  o.x = f2bf(f.x); o.y = f2bf(f.y); o.z = f2bf(f.z); o.w = f2bf(f.w);
  *(ushort4*)&d[i] = o;
}

// ---------------- kernel 2: weight transpose + convert: W[k][n] -> Wt[n][k] bf16 ----
__global__ void wtrans(const float* __restrict__ w0, const float* __restrict__ w1,
                       const float* __restrict__ w2, const float* __restrict__ w3,
                       u16* __restrict__ o0, u16* __restrict__ o1,
                       u16* __restrict__ o2, u16* __restrict__ o3) {
  const int z = blockIdx.z;
  const float* in = z == 0 ? w0 : (z == 1 ? w1 : (z == 2 ? w2 : w3));
  u16* out = z == 0 ? o0 : (z == 1 ? o1 : (z == 2 ? o2 : o3));
  __shared__ float tile[32][33];
  const int bx = blockIdx.x * 32, by = blockIdx.y * 32;
  for (int i = threadIdx.y; i < 32; i += 8)
    tile[i][threadIdx.x] = in[(size_t)(by + i) * 1024 + bx + threadIdx.x];
  __syncthreads();
  for (int i = threadIdx.y; i < 32; i += 8)
    out[(size_t)(bx + i) * 1024 + by + threadIdx.x] = f2bf(tile[threadIdx.x][i]);
}

// ---------------- GEMM: C[8192,1024] = A[8192,1024] @ Bt[1024,1024]^T + bias ------
// m97 structure: 128x128 tile, BK=32, global_load_lds width 16, 4 waves, 4x4 MFMA/wave
// mode 0: fp32 [m][n];  mode 1: bf16 split [B,H,S,DK];  mode 2: bf16 V^T [B,H,DK,S]
__device__ __forceinline__ void gemm_body(const u16* __restrict__ A, const u16* __restrict__ Bt,
                                          const float* __restrict__ bias, float alpha,
                                          int mode, void* __restrict__ outp) {
  __shared__ __align__(16) u16 As[128 * 32];
  __shared__ __align__(16) u16 Bs[128 * 32];
  const int t = threadIdx.x, wave = t >> 6, lane = t & 63;
  const int m0 = blockIdx.y * 128, n0 = blockIdx.x * 128;
  const int wm = (wave >> 1) * 64, wn = (wave & 1) * 64;
  const int lrow = lane >> 2, lcol = (lane & 3) * 8;
  f32x4 acc[4][4] = {};
  for (int k0 = 0; k0 < 1024; k0 += 32) {
    __syncthreads();
#pragma unroll
    for (int c = 0; c < 2; ++c) {
      const int chunk = wave * 2 + c;
      const int row = chunk * 16 + lrow;
      async16(&A[(size_t)(m0 + row) * 1024 + k0 + lcol], &As[chunk * 512]);
      async16(&Bt[(size_t)(n0 + row) * 1024 + k0 + lcol], &Bs[chunk * 512]);
    }
    __syncthreads();
    short8 af[4], bf[4];
#pragma unroll
    for (int mb = 0; mb < 4; ++mb)
      af[mb] = *(const short8*)&As[(wm + mb * 16 + (lane & 15)) * 32 + (lane >> 4) * 8];
#pragma unroll
    for (int nb = 0; nb < 4; ++nb)
      bf[nb] = *(const short8*)&Bs[(wn + nb * 16 + (lane & 15)) * 32 + (lane >> 4) * 8];
#pragma unroll
    for (int mb = 0; mb < 4; ++mb)
#pragma unroll
      for (int nb = 0; nb < 4; ++nb)
        acc[mb][nb] = mfma32(af[mb], bf[nb], acc[mb][nb]);
  }
#pragma unroll
  for (int mb = 0; mb < 4; ++mb)
#pragma unroll
    for (int nb = 0; nb < 4; ++nb) {
      const int n = n0 + wn + nb * 16 + (lane & 15);
      const float bn = bias[n];
      if (mode == 2) {
        // V^T [B*H, DK, S]: r -> s contiguous, pack 4 into one 8B store
        const int h = n >> 6, d = n & 63;
        const int mbase = m0 + wm + mb * 16 + (lane >> 4) * 4;
        const int b = mbase >> 11, s = mbase & 2047;
        union { unsigned int u[2]; ushort4 s4; } pk;
        pk.u[0] = pkbf(acc[mb][nb][0] + bn, acc[mb][nb][1] + bn);
        pk.u[1] = pkbf(acc[mb][nb][2] + bn, acc[mb][nb][3] + bn);
        *(ushort4*)&((u16*)outp)[(size_t)((b * 16 + h) * 64 + d) * 2048 + s] = pk.s4;
      } else if (mode == 1) {
#pragma unroll
        for (int r = 0; r < 4; ++r) {
          const int m = m0 + wm + mb * 16 + (lane >> 4) * 4 + r;
          const int b = m >> 11, s = m & 2047, h = n >> 6, d = n & 63;
          ((u16*)outp)[(size_t)((b * 16 + h) * 2048 + s) * 64 + d] =
              f2bf(acc[mb][nb][r] * alpha + bn * alpha);
        }
      } else {
#pragma unroll
        for (int r = 0; r < 4; ++r) {
          const int m = m0 + wm + mb * 16 + (lane >> 4) * 4 + r;
          ((float*)outp)[(size_t)m * 1024 + n] = acc[mb][nb][r] + bn;
        }
      }
    }
}

__global__ __launch_bounds__(256, 3) void gemm_proj(
    const u16* xq, const u16* xk, const u16* xv,
    const u16* wq, const u16* wk, const u16* wv,
    const float* bq, const float* bk, const float* bv,
    u16* oq, u16* ok, u16* ov, float aq) {
  const int z = blockIdx.z;
  const u16* A = z == 0 ? xq : (z == 1 ? xk : xv);
  const u16* B = z == 0 ? wq : (z == 1 ? wk : wv);
  const float* bi = z == 0 ? bq : (z == 1 ? bk : bv);
  void* o = z == 0 ? (void*)oq : (z == 1 ? (void*)ok : (void*)ov);
  gemm_body(A, B, bi, z == 0 ? aq : 1.0f, z == 2 ? 2 : 1, o);
}

__global__ __launch_bounds__(256, 3) void gemm_out(const u16* A, const u16* Bt,
                                                   const float* bias, float* o) {
  gemm_body(A, Bt, bias, 1.0f, 0, o);
}

// ---------------- kernel 4: flash attention, S^T formulation, 64-q blocks --------
// grid (S/64, B*H); block 256 = 4 waves; wave owns 16 q rows (one q-group).
// No online max (logits bounded; softmax shift-invariant). l summed once at end.
// V arrives pre-transposed [B,H,DK,S]; K and V^T stage via async16 DMA.
// LDS XOR-chunk swizzle: 16B chunk c of row r at position c^(r&7).
// launch_bounds(256,4): (256,8) forced VGPR=32 -> scratch spill (R4: WRITE_SIZE
// 16->39 MB, dur flat). At natural ~56-64 VGPR we still get 8 waves/SIMD.
__global__ __launch_bounds__(256, 4) void flash_attn(const u16* __restrict__ Q,
                                                     const u16* __restrict__ K,
                                                     const u16* __restrict__ Vt,
                                                     u16* __restrict__ O) {
  __shared__ __align__(16) u16 lds[2 * 64 * 64];  // Ks [s][d] | Vs [d][s], swizzled
  u16* Ks = lds;
  u16* Vs = lds + 4096;
  const int t = threadIdx.x, wave = t >> 6, lane = t & 63;
  const int quad = lane >> 4, q15 = lane & 15, sw = q15 & 7;
  const int bh = blockIdx.y, q0 = blockIdx.x * 64;
  const u16* Qb = Q + (size_t)bh * 2048 * 64;
  const u16* Kb = K + (size_t)bh * 2048 * 64;
  const u16* Vb = Vt + (size_t)bh * 64 * 2048;
  // Q B-fragments, held all loop: B[n=q][k=d]
  const int qr = q0 + wave * 16 + q15;
  const short8 qf0 = *(const short8*)&Qb[(size_t)qr * 64 + quad * 8];
  const short8 qf1 = *(const short8*)&Qb[(size_t)qr * 64 + 32 + quad * 8];
  f32x4 oacc[4] = {};  // O^T[d = mb*16 + quad*4 + r][q = lane&15]
  float l = 0.f;
  for (int kc = 0; kc < 2048; kc += 64) {
    __syncthreads();
#pragma unroll
    for (int c = 0; c < 2; ++c) {
      const int i = wave * 2 + c;
      const int row = i * 8 + (lane >> 3);          // s-row for K, d-row for V^T
      const int ch = (lane & 7) ^ (row & 7);        // swizzle via SOURCE permutation
      async16(&Kb[(size_t)(kc + row) * 64 + ch * 8], &Ks[i * 512]);
      async16(&Vb[(size_t)row * 2048 + kc + ch * 8], &Vs[i * 512]);
    }
    __syncthreads();
    short4v pk[4];  // P^T C-frag == 16x16x16 B-frag — no LDS round-trip
#pragma unroll
    for (int ma = 0; ma < 4; ++ma) {
      const int rowo = (ma * 16 + q15) * 64;
      const short8 k0 = *(const short8*)&Ks[rowo + ((quad ^ sw) * 8)];
      const short8 k1 = *(const short8*)&Ks[rowo + (((4 + quad) ^ sw) * 8)];
      f32x4 s0 = {};
      s0 = mfma32(k0, qf0, s0);
      s0 = mfma32(k1, qf1, s0);
      float p0 = __builtin_exp2f(s0[0]);
      float p1 = __builtin_exp2f(s0[1]);
      float p2 = __builtin_exp2f(s0[2]);
      float p3 = __builtin_exp2f(s0[3]);
      l += (p0 + p1) + (p2 + p3);
      union { unsigned int u[2]; short4v s4; } pq;
      pq.u[0] = pkbf(p0, p1);
      pq.u[1] = pkbf(p2, p3);
      pk[ma] = pq.s4;
    }
    // O^T += V^T · P^T
#if __has_builtin(__builtin_amdgcn_mfma_f32_16x16x16bf16_1k)
#pragma unroll
    for (int mb = 0; mb < 4; ++mb) {
      const int vrow = (mb * 16 + q15) * 64;
#pragma unroll
      for (int kb = 0; kb < 4; ++kb) {
        const int pos = (((kb * 2 + (quad >> 1)) ^ sw) * 8) + (quad & 1) * 4;
        const short4v vf = *(const short4v*)&Vs[vrow + pos];
        oacc[mb] = __builtin_amdgcn_mfma_f32_16x16x16bf16_1k(vf, pk[kb], oacc[mb], 0, 0, 0);
      }
    }
#else
    // fallback: assemble x32 B-frags from pk via shuffles
    {
      const int* pi = (const int*)&pk[0];
#pragma unroll
      for (int kb2 = 0; kb2 < 2; ++kb2) {
        const int lo = quad < 2 ? pi[kb2 * 4 + 0] : pi[kb2 * 4 + 2];
        const int hi = quad < 2 ? pi[kb2 * 4 + 1] : pi[kb2 * 4 + 3];
        const int src = (2 * (quad & 1)) * 16 + q15;
        union { int i[4]; short8 s; } u;
        u.i[0] = __shfl(lo, src);      u.i[1] = __shfl(hi, src);
        u.i[2] = __shfl(lo, src + 16); u.i[3] = __shfl(hi, src + 16);
#pragma unroll
        for (int mb = 0; mb < 4; ++mb) {
          const short8 vf8 = *(const short8*)&Vs[(mb * 16 + q15) * 64 + (((kb2 * 4 + quad) ^ sw) * 8)];
          oacc[mb] = mfma32(vf8, u.s, oacc[mb]);
        }
      }
    }
#endif
  }
  l += __shfl_xor(l, 16);
  l += __shfl_xor(l, 32);
  const float inv = 1.f / l;
  // epilogue: un-transpose O^T via per-wave LDS tile (16x64), write [B,S,H*DK] bf16
  __syncthreads();               // other waves done reading Ks/Vs of last chunk
  u16* Es = lds + wave * 1024;   // 2 KB per wave
#pragma unroll
  for (int mb = 0; mb < 4; ++mb) {
    const int posc = ((mb * 2 + (quad >> 1)) ^ sw) * 8 + (quad & 1) * 4;
    union { unsigned int u[2]; ushort4 s4; } pq;
    pq.u[0] = pkbf(oacc[mb][0] * inv, oacc[mb][1] * inv);
    pq.u[1] = pkbf(oacc[mb][2] * inv, oacc[mb][3] * inv);
    *(ushort4*)&Es[q15 * 64 + posc] = pq.s4;
  }
  // wave-local write->read: compiler inserts lgkmcnt wait; no cross-wave dependency
  const int b = bh >> 4, h = bh & 15;
#pragma unroll
  for (int pass = 0; pass < 2; ++pass) {
    const int rw = pass * 8 + (lane >> 3);
    const int j = lane & 7;
    const short8 val = *(const short8*)&Es[rw * 64 + ((j ^ (rw & 7)) * 8)];
    *(short8*)&O[((size_t)(b * 2048 + q0 + wave * 16 + rw)) * 1024 + h * 64 + j * 8] = val;
  }
}

// ---------------- host launcher ----------------
extern "C" void kernel_launch(void* const* d_in, const int* in_sizes, int n_in,
                              void* d_out, int out_size, void* d_ws, size_t ws_size,
                              hipStream_t stream) {
  const float* q_in = (const float*)d_in[0];
  const float* v_in = (const float*)d_in[1];
  const float* k_in = (const float*)d_in[2];
  const float* Wq = (const float*)d_in[3];
  const float* bq = (const float*)d_in[4];
  const float* Wk = (const float*)d_in[5];
  const float* bk = (const float*)d_in[6];
  const float* Wv = (const float*)d_in[7];
  const float* bv = (const float*)d_in[8];
  const float* Wo = (const float*)d_in[9];
  const float* bo = (const float*)d_in[10];
  float* out = (float*)d_out;
  char* ws = (char*)d_ws;

  u16* xq = (u16*)(ws);                 // 16 MB  (bf16 activations)
  u16* xk = (u16*)(ws + 16 * (size_t)MB_);
  u16* xv = (u16*)(ws + 32 * (size_t)MB_);
  u16* wqT = (u16*)(ws + 48 * (size_t)MB_);  // 2 MB each (bf16 W^T)
  u16* wkT = (u16*)(ws + 50 * (size_t)MB_);
  u16* wvT = (u16*)(ws + 52 * (size_t)MB_);
  u16* woT = (u16*)(ws + 54 * (size_t)MB_);
  u16* qb = (u16*)(ws + 56 * (size_t)MB_);   // [B,H,S,DK] bf16
  u16* kb = (u16*)(ws + 72 * (size_t)MB_);   // [B,H,S,DK] bf16
  u16* vb = (u16*)(ws + 88 * (size_t)MB_);   // [B,H,DK,S] bf16 (pre-transposed)
  u16* ao = xq;  // attention output reuses xq (dead after projections)

  // fold softmax scale and log2(e) into Q so the inner loop uses raw exp2
  const float aq = 0.125f * 1.44269504088896340736f;

  cvt_x<<<dim3(8192, 3), 256, 0, stream>>>(q_in, k_in, v_in, xq, xk, xv);
  wtrans<<<dim3(32, 32, 4), dim3(32, 8), 0, stream>>>(Wq, Wk, Wv, Wo, wqT, wkT, wvT, woT);
  gemm_proj<<<dim3(8, 64, 3), 256, 0, stream>>>(xq, xk, xv, wqT, wkT, wvT, bq, bk, bv, qb, kb, vb, aq);
  flash_attn<<<dim3(32, 64), 256, 0, stream>>>(qb, kb, vb, ao);
  gemm_out<<<dim3(8, 64), 256, 0, stream>>>(ao, woT, bo, out);
}